// Round 1
// baseline (1126.864 us; speedup 1.0000x reference)
//
#include <hip/hip_runtime.h>
#include <cstdint>
#include <cstddef>

// Problem constants: B=16, Adim=Bdim=512(CDIM), E=256, An=Bn=2048(NDIM)
#define BATCH 16
#define CDIM 512
#define EDIM 256
#define NDIM 2048

typedef short bf16x8 __attribute__((ext_vector_type(8)));
typedef float f32x4 __attribute__((ext_vector_type(4)));

__device__ __forceinline__ unsigned short f2bf(float f) {
  union { float f; unsigned int u; } v; v.f = f;
  unsigned int r = v.u + 0x7fffu + ((v.u >> 16) & 1u);
  return (unsigned short)(r >> 16);
}

// ---------------------------------------------------------------------------
// cast_f32_bf16: flat f32 -> bf16 (for the weight matrices). n divisible by 1024.
// ---------------------------------------------------------------------------
__global__ __launch_bounds__(256) void cast_f32_bf16(const float* __restrict__ x,
                                                     unsigned short* __restrict__ y) {
  const int i = (blockIdx.x * 256 + threadIdx.x) * 4;
  float4 v = *(const float4*)&x[i];
  ushort4 o;
  o.x = f2bf(v.x); o.y = f2bf(v.y); o.z = f2bf(v.z); o.w = f2bf(v.w);
  *(ushort4*)&y[i] = o;
}

// ---------------------------------------------------------------------------
// transpose_cast: X f32 [b][CDIM][NDIM] -> Xt bf16 [b][NDIM][CDIM]
// 32x32 tiles via LDS. grid (NDIM/32, CDIM/32, BATCH), block 256.
// ---------------------------------------------------------------------------
__global__ __launch_bounds__(256) void transpose_cast(const float* __restrict__ X,
                                                      unsigned short* __restrict__ Xt) {
  __shared__ float tile[32][33];
  const int b = blockIdx.z;
  const float* Xb = X + (size_t)b * CDIM * NDIM;
  unsigned short* Xtb = Xt + (size_t)b * CDIM * NDIM;
  const int n0 = blockIdx.x * 32, c0 = blockIdx.y * 32;
  const int tx = threadIdx.x & 31, ty = threadIdx.x >> 5;
#pragma unroll
  for (int i = 0; i < 4; ++i)
    tile[ty + i * 8][tx] = Xb[(size_t)(c0 + ty + i * 8) * NDIM + n0 + tx];
  __syncthreads();
  const int nl = threadIdx.x >> 3, c4 = (threadIdx.x & 7) * 4;
  ushort4 o;
  o.x = f2bf(tile[c4 + 0][nl]); o.y = f2bf(tile[c4 + 1][nl]);
  o.z = f2bf(tile[c4 + 2][nl]); o.w = f2bf(tile[c4 + 3][nl]);
  *(ushort4*)&Xtb[(size_t)(n0 + nl) * CDIM + c0 + c4] = o;
}

// ---------------------------------------------------------------------------
// gemm_nt_mfma: C[b][m][n] = scale * sum_k A[b][m][k] * B[b][n][k]
//   A: bf16 [M][K] row-major (batch stride sA elems; 0 = broadcast)
//   B: bf16 or f32 [N][K] row-major (B_IS_F32 -> converted during staging)
//   C: OUT_F32 -> f32 [M][N]; OUT_BF16 -> bf16 [M][N]; OUT_BF16T -> bf16 [N][M]
// 128x128 tile, BK=64, 4 waves, each wave 64x64 = 4x4 of 16x16x32 MFMA.
// LDS rows padded to 72 shorts (144B): conflict-free b128 fragment reads.
// MFMA layouts (m89-verified): A-frag elem j = A[m=lane&15][k=(lane>>4)*8+j];
// B-frag elem j = B[k=(lane>>4)*8+j][n=lane&15]; D reg r = C[(lane>>4)*4+r][lane&15].
// ---------------------------------------------------------------------------
enum { OUT_F32 = 0, OUT_BF16 = 1, OUT_BF16T = 2 };

template <int OUTMODE, bool B_IS_F32>
__global__ __launch_bounds__(256) void gemm_nt_mfma(
    const void* __restrict__ Ap, const void* __restrict__ Bptr, void* __restrict__ Cp,
    int M, int N, int K, long sA, long sB, long sC, float scale) {
  __shared__ alignas(16) short As[128 * 72];
  __shared__ alignas(16) short Bs[128 * 72];
  const int b = blockIdx.z;
  const int m0 = blockIdx.y * 128, n0 = blockIdx.x * 128;
  const unsigned short* A = (const unsigned short*)Ap + (size_t)sA * b;
  const int tid = threadIdx.x;
  const int lane = tid & 63, wid = tid >> 6;
  const int l16 = lane & 15, q = lane >> 4;
  const int wm = (wid >> 1) * 64, wn = (wid & 1) * 64;
  const int sr = tid >> 1, sh = tid & 1;  // staging: row, half-row (64B each)

  f32x4 acc[4][4];
#pragma unroll
  for (int i = 0; i < 4; ++i)
#pragma unroll
    for (int j = 0; j < 4; ++j) acc[i][j] = f32x4{0.f, 0.f, 0.f, 0.f};

  short* a_dst = &As[sr * 72 + sh * 32];
  short* b_dst = &Bs[sr * 72 + sh * 32];

  for (int k0 = 0; k0 < K; k0 += 64) {
    {  // stage A tile: 128 rows x 64 bf16, 2 threads/row, 64B contiguous each
      const unsigned short* src = A + (size_t)(m0 + sr) * K + k0 + sh * 32;
      int4 c0 = *(const int4*)(src);
      int4 c1 = *(const int4*)(src + 8);
      int4 c2 = *(const int4*)(src + 16);
      int4 c3 = *(const int4*)(src + 24);
      *(int4*)(a_dst) = c0;
      *(int4*)(a_dst + 8) = c1;
      *(int4*)(a_dst + 16) = c2;
      *(int4*)(a_dst + 24) = c3;
    }
    if (B_IS_F32) {  // stage B tile with f32 -> bf16 conversion
      const float* src = (const float*)Bptr + (size_t)sB * b + (size_t)(n0 + sr) * K + k0 + sh * 32;
#pragma unroll
      for (int c = 0; c < 8; ++c) {
        float4 v = *(const float4*)(src + c * 4);
        ushort4 o;
        o.x = f2bf(v.x); o.y = f2bf(v.y); o.z = f2bf(v.z); o.w = f2bf(v.w);
        *(ushort4*)(b_dst + c * 4) = o;
      }
    } else {
      const unsigned short* src =
          (const unsigned short*)Bptr + (size_t)sB * b + (size_t)(n0 + sr) * K + k0 + sh * 32;
      int4 c0 = *(const int4*)(src);
      int4 c1 = *(const int4*)(src + 8);
      int4 c2 = *(const int4*)(src + 16);
      int4 c3 = *(const int4*)(src + 24);
      *(int4*)(b_dst) = c0;
      *(int4*)(b_dst + 8) = c1;
      *(int4*)(b_dst + 16) = c2;
      *(int4*)(b_dst + 24) = c3;
    }
    __syncthreads();
#pragma unroll
    for (int kk = 0; kk < 2; ++kk) {
      bf16x8 af[4], bfr[4];
#pragma unroll
      for (int t = 0; t < 4; ++t)
        af[t] = *(const bf16x8*)&As[(wm + t * 16 + l16) * 72 + kk * 32 + q * 8];
#pragma unroll
      for (int t = 0; t < 4; ++t)
        bfr[t] = *(const bf16x8*)&Bs[(wn + t * 16 + l16) * 72 + kk * 32 + q * 8];
#pragma unroll
      for (int i = 0; i < 4; ++i)
#pragma unroll
        for (int j = 0; j < 4; ++j)
          acc[i][j] = __builtin_amdgcn_mfma_f32_16x16x32_bf16(af[i], bfr[j], acc[i][j], 0, 0, 0);
    }
    __syncthreads();
  }

  const int mb = m0 + wm + q * 4, nb = n0 + wn + l16;
  if (OUTMODE == OUT_F32) {
    float* C = (float*)Cp + (size_t)sC * b;
#pragma unroll
    for (int i = 0; i < 4; ++i)
#pragma unroll
      for (int j = 0; j < 4; ++j)
#pragma unroll
        for (int r = 0; r < 4; ++r)
          C[(size_t)(mb + i * 16 + r) * N + nb + j * 16] = acc[i][j][r] * scale;
  } else if (OUTMODE == OUT_BF16) {
    unsigned short* C = (unsigned short*)Cp + (size_t)sC * b;
#pragma unroll
    for (int i = 0; i < 4; ++i)
#pragma unroll
      for (int j = 0; j < 4; ++j)
#pragma unroll
        for (int r = 0; r < 4; ++r)
          C[(size_t)(mb + i * 16 + r) * N + nb + j * 16] = f2bf(acc[i][j][r]);
  } else {  // OUT_BF16T: store C[m][n] at Ct[n][m]; 4 regs = 4 consecutive m
    unsigned short* C = (unsigned short*)Cp + (size_t)sC * b;
#pragma unroll
    for (int i = 0; i < 4; ++i)
#pragma unroll
      for (int j = 0; j < 4; ++j) {
        ushort4 o;
        o.x = f2bf(acc[i][j][0]); o.y = f2bf(acc[i][j][1]);
        o.z = f2bf(acc[i][j][2]); o.w = f2bf(acc[i][j][3]);
        *(ushort4*)&C[(size_t)(nb + j * 16) * M + mb + i * 16] = o;
      }
  }
}

// ---------------------------------------------------------------------------
// g3_softmax: fused  att[b][a][m] = softmax_m( (1/16) sum_e A_t[a][e]*Bp_t[m][e] )
// Each block: 16 h-rows x full 2048 cols, K=256 resident.
//   - A slab 16x256 staged once to LDS -> 8 A-frags/lane in regs (32 VGPR)
//   - Bp streamed in 64-row x 256-col bf16 chunks, double-buffered LDS
//     (issue-early global->reg, MFMA, reg->LDS, one barrier per chunk)
//   - acc: 32 x f32x4 per lane (fully unrolled -> stays in registers)
//   - softmax: in-lane max/sum over 32 chunks, shfl_xor over 16-lane col group,
//     LDS cross-wave reduce, __expf, single f32 write of att.
// Saves the separate softmax pass (536 MB HBM round-trip). Bp_t is 1 MB/batch
// -> L2-resident across the 128 blocks of a batch (B re-reads hit L2).
// LDS 76.5 KB -> 2 blocks/CU; ~220 VGPR -> 2 waves/SIMD.
// ---------------------------------------------------------------------------
#define BPAD 264  // 256 + 8 pad: row stride 132 dw -> 4-bank shift/row

__global__ __launch_bounds__(256, 2) void g3_softmax(
    const unsigned short* __restrict__ At, const unsigned short* __restrict__ Bt,
    float* __restrict__ att) {
  __shared__ alignas(16) short As[16 * BPAD];
  __shared__ alignas(16) short Bs[2][64 * BPAD];
  __shared__ float redm[4][16];
  __shared__ float reds[4][16];

  const int b = blockIdx.y;
  const int a0 = blockIdx.x * 16;
  const unsigned short* Ab = At + (size_t)b * (NDIM * EDIM) + (size_t)a0 * EDIM;
  const unsigned short* Bb = Bt + (size_t)b * (NDIM * EDIM);
  const int tid = threadIdx.x;
  const int lane = tid & 63, w = tid >> 6;
  const int l16 = lane & 15, q = lane >> 4;

  {  // stage A slab: 16 rows x 256 bf16 (contiguous 8 KB), 32 shorts/thread
    const int r = tid >> 3, c4 = (tid & 7) * 32;
    const int4* src = (const int4*)(Ab + r * EDIM + c4);
    int4 v0 = src[0], v1 = src[1], v2 = src[2], v3 = src[3];
    int4* dst = (int4*)&As[r * BPAD + c4];
    dst[0] = v0; dst[1] = v1; dst[2] = v2; dst[3] = v3;
  }
  __syncthreads();
  bf16x8 af[8];  // A-frags for all 8 k-steps: A[m=l16][k=kk*32+q*8 ..]
#pragma unroll
  for (int kk = 0; kk < 8; ++kk)
    af[kk] = *(const bf16x8*)&As[l16 * BPAD + kk * 32 + q * 8];

  // B staging map: thread t covers 64 contiguous shorts (128 B) of the chunk
  const int br = tid >> 2, bc = (tid & 3) * 64;
  const unsigned short* bsrc0 = Bb + br * EDIM + bc;
  {  // stage chunk 0
    int4* dst = (int4*)&Bs[0][br * BPAD + bc];
    const int4* src = (const int4*)bsrc0;
#pragma unroll
    for (int i = 0; i < 8; ++i) dst[i] = src[i];
  }
  __syncthreads();

  f32x4 acc[32];
  const int bs_off = (w * 16 + l16) * BPAD;
#pragma unroll
  for (int c = 0; c < 32; ++c) {
    int4 stg[8];
    if (c < 31) {  // issue next chunk's global loads early (hide under MFMA)
      const int4* src = (const int4*)(bsrc0 + (size_t)(c + 1) * (64 * EDIM));
#pragma unroll
      for (int i = 0; i < 8; ++i) stg[i] = src[i];
    }
    const short* bp = &Bs[c & 1][bs_off];
    f32x4 e = f32x4{0.f, 0.f, 0.f, 0.f}, o = f32x4{0.f, 0.f, 0.f, 0.f};
#pragma unroll
    for (int kk = 0; kk < 8; kk += 2) {  // two independent MFMA chains
      bf16x8 b0 = *(const bf16x8*)(bp + kk * 32 + q * 8);
      bf16x8 b1 = *(const bf16x8*)(bp + (kk + 1) * 32 + q * 8);
      e = __builtin_amdgcn_mfma_f32_16x16x32_bf16(af[kk], b0, e, 0, 0, 0);
      o = __builtin_amdgcn_mfma_f32_16x16x32_bf16(af[kk + 1], b1, o, 0, 0, 0);
    }
    acc[c] = e + o;
    if (c < 31) {  // write-late into the other buffer
      int4* dst = (int4*)&Bs[(c + 1) & 1][br * BPAD + bc];
#pragma unroll
      for (int i = 0; i < 8; ++i) dst[i] = stg[i];
    }
    __syncthreads();  // one barrier per chunk covers RAW and WAR
  }

  // ---- softmax over the 2048 columns, rows a0 + q*4 + r ----
  float mr[4];
#pragma unroll
  for (int r = 0; r < 4; ++r) {
    float m = acc[0][r];
#pragma unroll
    for (int c = 1; c < 32; ++c) m = fmaxf(m, acc[c][r]);
#pragma unroll
    for (int off = 1; off < 16; off <<= 1) m = fmaxf(m, __shfl_xor(m, off));
    mr[r] = m;
  }
  if (l16 == 0) {
#pragma unroll
    for (int r = 0; r < 4; ++r) redm[w][q * 4 + r] = mr[r];
  }
  __syncthreads();
#pragma unroll
  for (int r = 0; r < 4; ++r) {
    const int row = q * 4 + r;
    mr[r] = fmaxf(fmaxf(redm[0][row], redm[1][row]),
                  fmaxf(redm[2][row], redm[3][row]));
  }
  float sr[4] = {0.f, 0.f, 0.f, 0.f};
#pragma unroll
  for (int c = 0; c < 32; ++c) {
#pragma unroll
    for (int r = 0; r < 4; ++r) {
      float p = __expf((acc[c][r] - mr[r]) * 0.0625f);
      acc[c][r] = p;
      sr[r] += p;
    }
  }
#pragma unroll
  for (int r = 0; r < 4; ++r)
#pragma unroll
    for (int off = 1; off < 16; off <<= 1) sr[r] += __shfl_xor(sr[r], off);
  if (l16 == 0) {
#pragma unroll
    for (int r = 0; r < 4; ++r) reds[w][q * 4 + r] = sr[r];
  }
  __syncthreads();
  float* ob = att + (size_t)b * NDIM * NDIM;
  const int colb = w * 16 + l16;
#pragma unroll
  for (int r = 0; r < 4; ++r) {
    const int row = q * 4 + r;
    const float inv = 1.0f / (reds[0][row] + reds[1][row] + reds[2][row] + reds[3][row]);
    float* orow = ob + (size_t)(a0 + row) * NDIM + colb;
#pragma unroll
    for (int c = 0; c < 32; ++c) orow[c * 64] = acc[c][r] * inv;
  }
}

// ---------------------------------------------------------------------------
// bn_stats / bn_norm: BatchNorm1d training-mode over (batch, positions).
// ---------------------------------------------------------------------------
__global__ __launch_bounds__(256) void bn_stats(const float* __restrict__ o,
                                                float* __restrict__ mean,
                                                float* __restrict__ rstd) {
  const int c = blockIdx.x;
  const int tid = threadIdx.x;
  float s = 0.f, sq = 0.f;
  for (int b = 0; b < BATCH; ++b) {
    const float4* p = (const float4*)(o + ((size_t)b * CDIM + c) * NDIM);
    float4 v = p[tid];
    float4 w = p[tid + 256];
    s += v.x + v.y + v.z + v.w + w.x + w.y + w.z + w.w;
    sq += v.x * v.x + v.y * v.y + v.z * v.z + v.w * v.w +
          w.x * w.x + w.y * w.y + w.z * w.z + w.w * w.w;
  }
#pragma unroll
  for (int off = 32; off; off >>= 1) {
    s += __shfl_down(s, off);
    sq += __shfl_down(sq, off);
  }
  __shared__ float rs[4], rq[4];
  if ((tid & 63) == 0) { rs[tid >> 6] = s; rq[tid >> 6] = sq; }
  __syncthreads();
  if (tid == 0) {
    s = rs[0] + rs[1] + rs[2] + rs[3];
    sq = rq[0] + rq[1] + rq[2] + rq[3];
    const float invn = 1.0f / (BATCH * NDIM);
    float mu = s * invn;
    float var = sq * invn - mu * mu;
    mean[c] = mu;
    rstd[c] = rsqrtf(var + 1e-5f);
  }
}

__global__ __launch_bounds__(256) void bn_norm(float* __restrict__ o,
                                               const float* __restrict__ mean,
                                               const float* __restrict__ rstd,
                                               const float* __restrict__ gamma,
                                               const float* __restrict__ beta) {
  const size_t i = (size_t)blockIdx.x * 256 + threadIdx.x;  // float4 index
  const int c = (int)((i >> 9) & (CDIM - 1));               // 512 float4 per row
  float4 v = ((float4*)o)[i];
  const float a = rstd[c] * gamma[c];
  const float d = beta[c] - mean[c] * a;
  v.x = v.x * a + d; v.y = v.y * a + d;
  v.z = v.z * a + d; v.w = v.w * a + d;
  ((float4*)o)[i] = v;
}

// ---------------------------------------------------------------------------
extern "C" void kernel_launch(void* const* d_in, const int* in_sizes, int n_in,
                              void* d_out, int out_size, void* d_ws, size_t ws_size,
                              hipStream_t stream) {
  const float* input_A = (const float*)d_in[0];  // [16,512,2048]
  const float* input_B = (const float*)d_in[1];  // [16,512,2048]
  const float* W_A   = (const float*)d_in[2];    // [256,512]
  const float* W_B   = (const float*)d_in[3];    // [256,512]
  const float* W_Bh  = (const float*)d_in[4];    // [256,512]
  const float* W_out = (const float*)d_in[5];    // [512,256]
  const float* gamma = (const float*)d_in[6];    // [512]
  const float* beta  = (const float*)d_in[7];    // [512]

  float* out = (float*)d_out;                      // [16,512,2048] f32
  float* att = out + (size_t)BATCH * CDIM * NDIM;  // [16,2048,2048] f32

  // Workspace layout (peak 84.9 MB < proven >=100.66 MB):
  char* w = (char*)d_ws;
  unsigned short* wA  = (unsigned short*)(w + 0);        // 256x512 bf16
  unsigned short* wB  = (unsigned short*)(w + 262144);
  unsigned short* wBh = (unsigned short*)(w + 524288);
  unsigned short* wO  = (unsigned short*)(w + 786432);   // 512x256 bf16
  float* mean = (float*)(w + 1048576);
  float* rstd = (float*)(w + 1050624);
  char* base = w + 1056768;
  unsigned short* X_At = (unsigned short*)(base);             // [16,2048,512] bf16, 33.55MB
  unsigned short* X_Bt = (unsigned short*)(base + 33554432);  // [16,2048,512] bf16
  unsigned short* A_t  = (unsigned short*)(base + 67108864);  // [16,2048,256] bf16
  unsigned short* Bp_t = (unsigned short*)(base);             // over dead X_At (1st half)
  unsigned short* Bh   = (unsigned short*)(base + 16777216);  // over dead X_At (2nd half)
  unsigned short* oute = (unsigned short*)(base + 67108864);  // over dead A_t: [16,2048,256]

  const dim3 blk(256);

  // Weight casts (131072 elems each = 128 blocks x 1024)
  cast_f32_bf16<<<dim3(128), blk, 0, stream>>>(W_A, wA);
  cast_f32_bf16<<<dim3(128), blk, 0, stream>>>(W_B, wB);
  cast_f32_bf16<<<dim3(128), blk, 0, stream>>>(W_Bh, wBh);
  cast_f32_bf16<<<dim3(128), blk, 0, stream>>>(W_out, wO);

  // Input transpose+cast: [b][512][2048] f32 -> [b][2048][512] bf16
  transpose_cast<<<dim3(64, 16, BATCH), blk, 0, stream>>>(input_A, X_At);
  transpose_cast<<<dim3(64, 16, BATCH), blk, 0, stream>>>(input_B, X_Bt);

  // G1a: A_t[a][e] = sum_c X_At[a][c] * W_A[e][c]   (M=2048,N=256,K=512)
  gemm_nt_mfma<OUT_BF16, false><<<dim3(2, 16, BATCH), blk, 0, stream>>>(
      X_At, wA, A_t, 2048, 256, 512, 1048576, 0, 524288, 1.f);
  // G1b: Bp_t[m][e] = sum_c X_Bt[m][c] * W_B[e][c]  (writes over dead X_At)
  gemm_nt_mfma<OUT_BF16, false><<<dim3(2, 16, BATCH), blk, 0, stream>>>(
      X_Bt, wB, Bp_t, 2048, 256, 512, 1048576, 0, 524288, 1.f);
  // G2: Bh[e][m] = sum_c W_Bh[e][c] * X_Bt[m][c]    (M=256,N=2048,K=512)
  gemm_nt_mfma<OUT_BF16, false><<<dim3(16, 2, BATCH), blk, 0, stream>>>(
      wBh, X_Bt, Bh, 256, 2048, 512, 0, 1048576, 524288, 1.f);

  // G3+softmax fused: att[a][m] = softmax_m( A_t . Bp_t^T / 16 ), single write
  g3_softmax<<<dim3(128, BATCH), blk, 0, stream>>>(A_t, Bp_t, att);

  // G4: oute_t[a][e] = sum_m Bh[e][m] * att[a][m]  (B=att f32, converted in staging;
  //     transposed bf16 epilogue). M=256, N=2048, K=2048.
  gemm_nt_mfma<OUT_BF16T, true><<<dim3(16, 2, BATCH), blk, 0, stream>>>(
      Bh, att, oute, 256, 2048, 2048, 524288, 4194304, 524288, 1.f);

  // G5: out[c][a] = sum_e W_out[c][e] * oute_t[a][e]  (M=512,N=2048,K=256) -> f32
  gemm_nt_mfma<OUT_F32, false><<<dim3(16, 4, BATCH), blk, 0, stream>>>(
      wO, oute, out, 512, 2048, 256, 0, 524288, 1048576, 1.f);

  // BatchNorm (training-mode batch stats), two-pass
  bn_stats<<<dim3(CDIM), blk, 0, stream>>>(out, mean, rstd);
  bn_norm<<<dim3(16384), blk, 0, stream>>>(out, mean, rstd, gamma, beta);
}

// Round 2
// 885.101 us; speedup vs baseline: 1.2731x; 1.2731x over previous
//
#include <hip/hip_runtime.h>
#include <cstdint>
#include <cstddef>

// Problem constants: B=16, Adim=Bdim=512(CDIM), E=256, An=Bn=2048(NDIM)
#define BATCH 16
#define CDIM 512
#define EDIM 256
#define NDIM 2048

typedef short bf16x8 __attribute__((ext_vector_type(8)));
typedef float f32x4 __attribute__((ext_vector_type(4)));

__device__ __forceinline__ unsigned short f2bf(float f) {
  union { float f; unsigned int u; } v; v.f = f;
  unsigned int r = v.u + 0x7fffu + ((v.u >> 16) & 1u);
  return (unsigned short)(r >> 16);
}

// ---------------------------------------------------------------------------
// cast_f32_bf16: flat f32 -> bf16 (for the weight matrices). n divisible by 1024.
// ---------------------------------------------------------------------------
__global__ __launch_bounds__(256) void cast_f32_bf16(const float* __restrict__ x,
                                                     unsigned short* __restrict__ y) {
  const int i = (blockIdx.x * 256 + threadIdx.x) * 4;
  float4 v = *(const float4*)&x[i];
  ushort4 o;
  o.x = f2bf(v.x); o.y = f2bf(v.y); o.z = f2bf(v.z); o.w = f2bf(v.w);
  *(ushort4*)&y[i] = o;
}

// ---------------------------------------------------------------------------
// transpose_cast: X f32 [b][CDIM][NDIM] -> Xt bf16 [b][NDIM][CDIM]
// 32x32 tiles via LDS. grid (NDIM/32, CDIM/32, BATCH), block 256.
// ---------------------------------------------------------------------------
__global__ __launch_bounds__(256) void transpose_cast(const float* __restrict__ X,
                                                      unsigned short* __restrict__ Xt) {
  __shared__ float tile[32][33];
  const int b = blockIdx.z;
  const float* Xb = X + (size_t)b * CDIM * NDIM;
  unsigned short* Xtb = Xt + (size_t)b * CDIM * NDIM;
  const int n0 = blockIdx.x * 32, c0 = blockIdx.y * 32;
  const int tx = threadIdx.x & 31, ty = threadIdx.x >> 5;
#pragma unroll
  for (int i = 0; i < 4; ++i)
    tile[ty + i * 8][tx] = Xb[(size_t)(c0 + ty + i * 8) * NDIM + n0 + tx];
  __syncthreads();
  const int nl = threadIdx.x >> 3, c4 = (threadIdx.x & 7) * 4;
  ushort4 o;
  o.x = f2bf(tile[c4 + 0][nl]); o.y = f2bf(tile[c4 + 1][nl]);
  o.z = f2bf(tile[c4 + 2][nl]); o.w = f2bf(tile[c4 + 3][nl]);
  *(ushort4*)&Xtb[(size_t)(n0 + nl) * CDIM + c0 + c4] = o;
}

// ---------------------------------------------------------------------------
// gemm_nt_mfma: C[b][m][n] = scale * sum_k A[b][m][k] * B[b][n][k]
//   A: bf16 [M][K] row-major (batch stride sA elems; 0 = broadcast)
//   B: bf16 or f32 [N][K] row-major (B_IS_F32 -> converted during staging)
//   C: OUT_F32 -> f32 [M][N]; OUT_BF16 -> bf16 [M][N]; OUT_BF16T -> bf16 [N][M]
// 128x128 tile, BK=64, 4 waves, each wave 64x64 = 4x4 of 16x16x32 MFMA.
// LDS rows padded to 72 shorts (144B): conflict-free b128 fragment reads.
// MFMA layouts (m89-verified): A-frag elem j = A[m=lane&15][k=(lane>>4)*8+j];
// B-frag elem j = B[k=(lane>>4)*8+j][n=lane&15]; D reg r = C[(lane>>4)*4+r][lane&15].
// ---------------------------------------------------------------------------
enum { OUT_F32 = 0, OUT_BF16 = 1, OUT_BF16T = 2 };

template <int OUTMODE, bool B_IS_F32>
__global__ __launch_bounds__(256) void gemm_nt_mfma(
    const void* __restrict__ Ap, const void* __restrict__ Bptr, void* __restrict__ Cp,
    int M, int N, int K, long sA, long sB, long sC, float scale) {
  __shared__ alignas(16) short As[128 * 72];
  __shared__ alignas(16) short Bs[128 * 72];
  const int b = blockIdx.z;
  const int m0 = blockIdx.y * 128, n0 = blockIdx.x * 128;
  const unsigned short* A = (const unsigned short*)Ap + (size_t)sA * b;
  const int tid = threadIdx.x;
  const int lane = tid & 63, wid = tid >> 6;
  const int l16 = lane & 15, q = lane >> 4;
  const int wm = (wid >> 1) * 64, wn = (wid & 1) * 64;
  const int sr = tid >> 1, sh = tid & 1;  // staging: row, half-row (64B each)

  f32x4 acc[4][4];
#pragma unroll
  for (int i = 0; i < 4; ++i)
#pragma unroll
    for (int j = 0; j < 4; ++j) acc[i][j] = f32x4{0.f, 0.f, 0.f, 0.f};

  short* a_dst = &As[sr * 72 + sh * 32];
  short* b_dst = &Bs[sr * 72 + sh * 32];

  for (int k0 = 0; k0 < K; k0 += 64) {
    {  // stage A tile: 128 rows x 64 bf16, 2 threads/row, 64B contiguous each
      const unsigned short* src = A + (size_t)(m0 + sr) * K + k0 + sh * 32;
      int4 c0 = *(const int4*)(src);
      int4 c1 = *(const int4*)(src + 8);
      int4 c2 = *(const int4*)(src + 16);
      int4 c3 = *(const int4*)(src + 24);
      *(int4*)(a_dst) = c0;
      *(int4*)(a_dst + 8) = c1;
      *(int4*)(a_dst + 16) = c2;
      *(int4*)(a_dst + 24) = c3;
    }
    if (B_IS_F32) {  // stage B tile with f32 -> bf16 conversion
      const float* src = (const float*)Bptr + (size_t)sB * b + (size_t)(n0 + sr) * K + k0 + sh * 32;
#pragma unroll
      for (int c = 0; c < 8; ++c) {
        float4 v = *(const float4*)(src + c * 4);
        ushort4 o;
        o.x = f2bf(v.x); o.y = f2bf(v.y); o.z = f2bf(v.z); o.w = f2bf(v.w);
        *(ushort4*)(b_dst + c * 4) = o;
      }
    } else {
      const unsigned short* src =
          (const unsigned short*)Bptr + (size_t)sB * b + (size_t)(n0 + sr) * K + k0 + sh * 32;
      int4 c0 = *(const int4*)(src);
      int4 c1 = *(const int4*)(src + 8);
      int4 c2 = *(const int4*)(src + 16);
      int4 c3 = *(const int4*)(src + 24);
      *(int4*)(b_dst) = c0;
      *(int4*)(b_dst + 8) = c1;
      *(int4*)(b_dst + 16) = c2;
      *(int4*)(b_dst + 24) = c3;
    }
    __syncthreads();
#pragma unroll
    for (int kk = 0; kk < 2; ++kk) {
      bf16x8 af[4], bfr[4];
#pragma unroll
      for (int t = 0; t < 4; ++t)
        af[t] = *(const bf16x8*)&As[(wm + t * 16 + l16) * 72 + kk * 32 + q * 8];
#pragma unroll
      for (int t = 0; t < 4; ++t)
        bfr[t] = *(const bf16x8*)&Bs[(wn + t * 16 + l16) * 72 + kk * 32 + q * 8];
#pragma unroll
      for (int i = 0; i < 4; ++i)
#pragma unroll
        for (int j = 0; j < 4; ++j)
          acc[i][j] = __builtin_amdgcn_mfma_f32_16x16x32_bf16(af[i], bfr[j], acc[i][j], 0, 0, 0);
    }
    __syncthreads();
  }

  const int mb = m0 + wm + q * 4, nb = n0 + wn + l16;
  if (OUTMODE == OUT_F32) {
    float* C = (float*)Cp + (size_t)sC * b;
#pragma unroll
    for (int i = 0; i < 4; ++i)
#pragma unroll
      for (int j = 0; j < 4; ++j)
#pragma unroll
        for (int r = 0; r < 4; ++r)
          C[(size_t)(mb + i * 16 + r) * N + nb + j * 16] = acc[i][j][r] * scale;
  } else if (OUTMODE == OUT_BF16) {
    unsigned short* C = (unsigned short*)Cp + (size_t)sC * b;
#pragma unroll
    for (int i = 0; i < 4; ++i)
#pragma unroll
      for (int j = 0; j < 4; ++j)
#pragma unroll
        for (int r = 0; r < 4; ++r)
          C[(size_t)(mb + i * 16 + r) * N + nb + j * 16] = f2bf(acc[i][j][r]);
  } else {  // OUT_BF16T: store C[m][n] at Ct[n][m]; 4 regs = 4 consecutive m
    unsigned short* C = (unsigned short*)Cp + (size_t)sC * b;
#pragma unroll
    for (int i = 0; i < 4; ++i)
#pragma unroll
      for (int j = 0; j < 4; ++j) {
        ushort4 o;
        o.x = f2bf(acc[i][j][0]); o.y = f2bf(acc[i][j][1]);
        o.z = f2bf(acc[i][j][2]); o.w = f2bf(acc[i][j][3]);
        *(ushort4*)&C[(size_t)(nb + j * 16) * M + mb + i * 16] = o;
      }
  }
}

// ---------------------------------------------------------------------------
// g3_softmax v2: att[b][a][m] = softmax_m( (1/16) sum_e A_t[a][e]*Bp_t[m][e] )
// Block = 512 threads (8 waves) x 16 a-rows x full 2048 cols. NO LDS staging:
// at 16 rows/block each B element feeds exactly one MFMA (zero reuse), so
// A-frags and B-frags are read DIRECTLY from global (Bp_t = 1 MB/batch ->
// L2-resident; A-slab 8 KB). Wave w owns col-tile w*16 of each 128-row chunk;
// 16 chunks. Accumulators are 16 NAMED f32x4 (macro-expanded -- guaranteed
// registers, no runtime indexing: round-1's acc[32] array spilled to scratch,
// VGPR_Count=92, 552us). No barriers in the MFMA loop; LDS only for the tiny
// cross-wave softmax reduce. Writes att exactly once (f32).
// ---------------------------------------------------------------------------
__global__ __launch_bounds__(512, 2) void g3_softmax(
    const unsigned short* __restrict__ At, const unsigned short* __restrict__ Bt,
    float* __restrict__ att) {
  __shared__ float redm[8][16];
  __shared__ float reds[8][16];

  const int b = blockIdx.y;
  const int a0 = blockIdx.x * 16;
  const int tid = threadIdx.x;
  const int lane = tid & 63, w = tid >> 6;
  const int l16 = lane & 15, q = lane >> 4;

  const unsigned short* Ab = At + (size_t)b * (NDIM * EDIM) + (size_t)a0 * EDIM;
  const unsigned short* Bb = Bt + (size_t)b * (NDIM * EDIM);

  // A-frags: af[kk] elem j = A[m=l16][k=kk*32+q*8+j] (16B contiguous, L2-hot)
  const unsigned short* ap = Ab + l16 * EDIM + q * 8;
  const bf16x8 af0 = *(const bf16x8*)(ap + 0 * 32);
  const bf16x8 af1 = *(const bf16x8*)(ap + 1 * 32);
  const bf16x8 af2 = *(const bf16x8*)(ap + 2 * 32);
  const bf16x8 af3 = *(const bf16x8*)(ap + 3 * 32);
  const bf16x8 af4 = *(const bf16x8*)(ap + 4 * 32);
  const bf16x8 af5 = *(const bf16x8*)(ap + 5 * 32);
  const bf16x8 af6 = *(const bf16x8*)(ap + 6 * 32);
  const bf16x8 af7 = *(const bf16x8*)(ap + 7 * 32);

  // B-frag base for this lane: row (chunk*128 + w*16 + l16), col q*8
  const unsigned short* bpbase = Bb + (size_t)(w * 16 + l16) * EDIM + q * 8;

#define G3_MFMA __builtin_amdgcn_mfma_f32_16x16x32_bf16
#define G3_CHUNK(C, ACC)                                                     \
  do {                                                                       \
    const unsigned short* bp_ = bpbase + (size_t)(C) * (128 * EDIM);         \
    bf16x8 b0_ = *(const bf16x8*)(bp_ + 0 * 32);                             \
    bf16x8 b1_ = *(const bf16x8*)(bp_ + 1 * 32);                             \
    bf16x8 b2_ = *(const bf16x8*)(bp_ + 2 * 32);                             \
    bf16x8 b3_ = *(const bf16x8*)(bp_ + 3 * 32);                             \
    bf16x8 b4_ = *(const bf16x8*)(bp_ + 4 * 32);                             \
    bf16x8 b5_ = *(const bf16x8*)(bp_ + 5 * 32);                             \
    bf16x8 b6_ = *(const bf16x8*)(bp_ + 6 * 32);                             \
    bf16x8 b7_ = *(const bf16x8*)(bp_ + 7 * 32);                             \
    f32x4 e_ = G3_MFMA(af0, b0_, f32x4{0.f, 0.f, 0.f, 0.f}, 0, 0, 0);        \
    f32x4 o_ = G3_MFMA(af1, b1_, f32x4{0.f, 0.f, 0.f, 0.f}, 0, 0, 0);        \
    e_ = G3_MFMA(af2, b2_, e_, 0, 0, 0);                                     \
    o_ = G3_MFMA(af3, b3_, o_, 0, 0, 0);                                     \
    e_ = G3_MFMA(af4, b4_, e_, 0, 0, 0);                                     \
    o_ = G3_MFMA(af5, b5_, o_, 0, 0, 0);                                     \
    e_ = G3_MFMA(af6, b6_, e_, 0, 0, 0);                                     \
    o_ = G3_MFMA(af7, b7_, o_, 0, 0, 0);                                     \
    ACC = e_ + o_;                                                           \
  } while (0)

  f32x4 acc0, acc1, acc2, acc3, acc4, acc5, acc6, acc7;
  f32x4 acc8, acc9, acc10, acc11, acc12, acc13, acc14, acc15;
  G3_CHUNK(0, acc0);   G3_CHUNK(1, acc1);   G3_CHUNK(2, acc2);
  G3_CHUNK(3, acc3);   G3_CHUNK(4, acc4);   G3_CHUNK(5, acc5);
  G3_CHUNK(6, acc6);   G3_CHUNK(7, acc7);   G3_CHUNK(8, acc8);
  G3_CHUNK(9, acc9);   G3_CHUNK(10, acc10); G3_CHUNK(11, acc11);
  G3_CHUNK(12, acc12); G3_CHUNK(13, acc13); G3_CHUNK(14, acc14);
  G3_CHUNK(15, acc15);

  // ---- softmax over 2048 cols; lane holds rows a0+q*4+r, r=0..3 ----
  float mr0 = acc0[0], mr1 = acc0[1], mr2 = acc0[2], mr3 = acc0[3];
#define G3_MAXA(ACC)                                                         \
  do {                                                                       \
    mr0 = fmaxf(mr0, ACC[0]); mr1 = fmaxf(mr1, ACC[1]);                      \
    mr2 = fmaxf(mr2, ACC[2]); mr3 = fmaxf(mr3, ACC[3]);                      \
  } while (0)
  G3_MAXA(acc1);  G3_MAXA(acc2);  G3_MAXA(acc3);  G3_MAXA(acc4);
  G3_MAXA(acc5);  G3_MAXA(acc6);  G3_MAXA(acc7);  G3_MAXA(acc8);
  G3_MAXA(acc9);  G3_MAXA(acc10); G3_MAXA(acc11); G3_MAXA(acc12);
  G3_MAXA(acc13); G3_MAXA(acc14); G3_MAXA(acc15);
#pragma unroll
  for (int off = 1; off < 16; off <<= 1) {
    mr0 = fmaxf(mr0, __shfl_xor(mr0, off));
    mr1 = fmaxf(mr1, __shfl_xor(mr1, off));
    mr2 = fmaxf(mr2, __shfl_xor(mr2, off));
    mr3 = fmaxf(mr3, __shfl_xor(mr3, off));
  }
  if (l16 == 0) {
    redm[w][q * 4 + 0] = mr0; redm[w][q * 4 + 1] = mr1;
    redm[w][q * 4 + 2] = mr2; redm[w][q * 4 + 3] = mr3;
  }
  __syncthreads();
#define G3_RED8(ARR, R)                                                       \
  fmaxf(fmaxf(fmaxf(ARR[0][R], ARR[1][R]), fmaxf(ARR[2][R], ARR[3][R])),      \
        fmaxf(fmaxf(ARR[4][R], ARR[5][R]), fmaxf(ARR[6][R], ARR[7][R])))
  mr0 = G3_RED8(redm, q * 4 + 0);
  mr1 = G3_RED8(redm, q * 4 + 1);
  mr2 = G3_RED8(redm, q * 4 + 2);
  mr3 = G3_RED8(redm, q * 4 + 3);

  float sr0 = 0.f, sr1 = 0.f, sr2 = 0.f, sr3 = 0.f;
#define G3_EXPA(ACC)                                                         \
  do {                                                                       \
    ACC[0] = __expf((ACC[0] - mr0) * 0.0625f); sr0 += ACC[0];                \
    ACC[1] = __expf((ACC[1] - mr1) * 0.0625f); sr1 += ACC[1];                \
    ACC[2] = __expf((ACC[2] - mr2) * 0.0625f); sr2 += ACC[2];                \
    ACC[3] = __expf((ACC[3] - mr3) * 0.0625f); sr3 += ACC[3];                \
  } while (0)
  G3_EXPA(acc0);  G3_EXPA(acc1);  G3_EXPA(acc2);  G3_EXPA(acc3);
  G3_EXPA(acc4);  G3_EXPA(acc5);  G3_EXPA(acc6);  G3_EXPA(acc7);
  G3_EXPA(acc8);  G3_EXPA(acc9);  G3_EXPA(acc10); G3_EXPA(acc11);
  G3_EXPA(acc12); G3_EXPA(acc13); G3_EXPA(acc14); G3_EXPA(acc15);
#pragma unroll
  for (int off = 1; off < 16; off <<= 1) {
    sr0 += __shfl_xor(sr0, off);
    sr1 += __shfl_xor(sr1, off);
    sr2 += __shfl_xor(sr2, off);
    sr3 += __shfl_xor(sr3, off);
  }
  if (l16 == 0) {
    reds[w][q * 4 + 0] = sr0; reds[w][q * 4 + 1] = sr1;
    reds[w][q * 4 + 2] = sr2; reds[w][q * 4 + 3] = sr3;
  }
  __syncthreads();
#define G3_SUM8(ARR, R)                                                      \
  (((ARR[0][R] + ARR[1][R]) + (ARR[2][R] + ARR[3][R])) +                     \
   ((ARR[4][R] + ARR[5][R]) + (ARR[6][R] + ARR[7][R])))
  const float inv0 = 1.0f / G3_SUM8(reds, q * 4 + 0);
  const float inv1 = 1.0f / G3_SUM8(reds, q * 4 + 1);
  const float inv2 = 1.0f / G3_SUM8(reds, q * 4 + 2);
  const float inv3 = 1.0f / G3_SUM8(reds, q * 4 + 3);

  float* ob = att + (size_t)b * NDIM * NDIM + (size_t)a0 * NDIM + w * 16 + l16;
  float* orow0 = ob + (size_t)(q * 4 + 0) * NDIM;
  float* orow1 = ob + (size_t)(q * 4 + 1) * NDIM;
  float* orow2 = ob + (size_t)(q * 4 + 2) * NDIM;
  float* orow3 = ob + (size_t)(q * 4 + 3) * NDIM;
#define G3_WRA(C, ACC)                                                       \
  do {                                                                       \
    orow0[(C) * 128] = ACC[0] * inv0;                                        \
    orow1[(C) * 128] = ACC[1] * inv1;                                        \
    orow2[(C) * 128] = ACC[2] * inv2;                                        \
    orow3[(C) * 128] = ACC[3] * inv3;                                        \
  } while (0)
  G3_WRA(0, acc0);   G3_WRA(1, acc1);   G3_WRA(2, acc2);   G3_WRA(3, acc3);
  G3_WRA(4, acc4);   G3_WRA(5, acc5);   G3_WRA(6, acc6);   G3_WRA(7, acc7);
  G3_WRA(8, acc8);   G3_WRA(9, acc9);   G3_WRA(10, acc10); G3_WRA(11, acc11);
  G3_WRA(12, acc12); G3_WRA(13, acc13); G3_WRA(14, acc14); G3_WRA(15, acc15);
}

// ---------------------------------------------------------------------------
// bn_stats / bn_norm: BatchNorm1d training-mode over (batch, positions).
// ---------------------------------------------------------------------------
__global__ __launch_bounds__(256) void bn_stats(const float* __restrict__ o,
                                                float* __restrict__ mean,
                                                float* __restrict__ rstd) {
  const int c = blockIdx.x;
  const int tid = threadIdx.x;
  float s = 0.f, sq = 0.f;
  for (int b = 0; b < BATCH; ++b) {
    const float4* p = (const float4*)(o + ((size_t)b * CDIM + c) * NDIM);
    float4 v = p[tid];
    float4 w = p[tid + 256];
    s += v.x + v.y + v.z + v.w + w.x + w.y + w.z + w.w;
    sq += v.x * v.x + v.y * v.y + v.z * v.z + v.w * v.w +
          w.x * w.x + w.y * w.y + w.z * w.z + w.w * w.w;
  }
#pragma unroll
  for (int off = 32; off; off >>= 1) {
    s += __shfl_down(s, off);
    sq += __shfl_down(sq, off);
  }
  __shared__ float rs[4], rq[4];
  if ((tid & 63) == 0) { rs[tid >> 6] = s; rq[tid >> 6] = sq; }
  __syncthreads();
  if (tid == 0) {
    s = rs[0] + rs[1] + rs[2] + rs[3];
    sq = rq[0] + rq[1] + rq[2] + rq[3];
    const float invn = 1.0f / (BATCH * NDIM);
    float mu = s * invn;
    float var = sq * invn - mu * mu;
    mean[c] = mu;
    rstd[c] = rsqrtf(var + 1e-5f);
  }
}

__global__ __launch_bounds__(256) void bn_norm(float* __restrict__ o,
                                               const float* __restrict__ mean,
                                               const float* __restrict__ rstd,
                                               const float* __restrict__ gamma,
                                               const float* __restrict__ beta) {
  const size_t i = (size_t)blockIdx.x * 256 + threadIdx.x;  // float4 index
  const int c = (int)((i >> 9) & (CDIM - 1));               // 512 float4 per row
  float4 v = ((float4*)o)[i];
  const float a = rstd[c] * gamma[c];
  const float d = beta[c] - mean[c] * a;
  v.x = v.x * a + d; v.y = v.y * a + d;
  v.z = v.z * a + d; v.w = v.w * a + d;
  ((float4*)o)[i] = v;
}

// ---------------------------------------------------------------------------
extern "C" void kernel_launch(void* const* d_in, const int* in_sizes, int n_in,
                              void* d_out, int out_size, void* d_ws, size_t ws_size,
                              hipStream_t stream) {
  const float* input_A = (const float*)d_in[0];  // [16,512,2048]
  const float* input_B = (const float*)d_in[1];  // [16,512,2048]
  const float* W_A   = (const float*)d_in[2];    // [256,512]
  const float* W_B   = (const float*)d_in[3];    // [256,512]
  const float* W_Bh  = (const float*)d_in[4];    // [256,512]
  const float* W_out = (const float*)d_in[5];    // [512,256]
  const float* gamma = (const float*)d_in[6];    // [512]
  const float* beta  = (const float*)d_in[7];    // [512]

  float* out = (float*)d_out;                      // [16,512,2048] f32
  float* att = out + (size_t)BATCH * CDIM * NDIM;  // [16,2048,2048] f32

  // Workspace layout (peak 84.9 MB < proven >=100.66 MB):
  char* w = (char*)d_ws;
  unsigned short* wA  = (unsigned short*)(w + 0);        // 256x512 bf16
  unsigned short* wB  = (unsigned short*)(w + 262144);
  unsigned short* wBh = (unsigned short*)(w + 524288);
  unsigned short* wO  = (unsigned short*)(w + 786432);   // 512x256 bf16
  float* mean = (float*)(w + 1048576);
  float* rstd = (float*)(w + 1050624);
  char* base = w + 1056768;
  unsigned short* X_At = (unsigned short*)(base);             // [16,2048,512] bf16, 33.55MB
  unsigned short* X_Bt = (unsigned short*)(base + 33554432);  // [16,2048,512] bf16
  unsigned short* A_t  = (unsigned short*)(base + 67108864);  // [16,2048,256] bf16
  unsigned short* Bp_t = (unsigned short*)(base);             // over dead X_At (1st half)
  unsigned short* Bh   = (unsigned short*)(base + 16777216);  // over dead X_At (2nd half)
  unsigned short* oute = (unsigned short*)(base + 67108864);  // over dead A_t: [16,2048,256]

  const dim3 blk(256);

  // Weight casts (131072 elems each = 128 blocks x 1024)
  cast_f32_bf16<<<dim3(128), blk, 0, stream>>>(W_A, wA);
  cast_f32_bf16<<<dim3(128), blk, 0, stream>>>(W_B, wB);
  cast_f32_bf16<<<dim3(128), blk, 0, stream>>>(W_Bh, wBh);
  cast_f32_bf16<<<dim3(128), blk, 0, stream>>>(W_out, wO);

  // Input transpose+cast: [b][512][2048] f32 -> [b][2048][512] bf16
  transpose_cast<<<dim3(64, 16, BATCH), blk, 0, stream>>>(input_A, X_At);
  transpose_cast<<<dim3(64, 16, BATCH), blk, 0, stream>>>(input_B, X_Bt);

  // G1a: A_t[a][e] = sum_c X_At[a][c] * W_A[e][c]   (M=2048,N=256,K=512)
  gemm_nt_mfma<OUT_BF16, false><<<dim3(2, 16, BATCH), blk, 0, stream>>>(
      X_At, wA, A_t, 2048, 256, 512, 1048576, 0, 524288, 1.f);
  // G1b: Bp_t[m][e] = sum_c X_Bt[m][c] * W_B[e][c]  (writes over dead X_At)
  gemm_nt_mfma<OUT_BF16, false><<<dim3(2, 16, BATCH), blk, 0, stream>>>(
      X_Bt, wB, Bp_t, 2048, 256, 512, 1048576, 0, 524288, 1.f);
  // G2: Bh[e][m] = sum_c W_Bh[e][c] * X_Bt[m][c]    (M=256,N=2048,K=512)
  gemm_nt_mfma<OUT_BF16, false><<<dim3(16, 2, BATCH), blk, 0, stream>>>(
      wBh, X_Bt, Bh, 256, 2048, 512, 0, 1048576, 524288, 1.f);

  // G3+softmax fused (v2, direct-global, register-resident): single att write
  g3_softmax<<<dim3(128, BATCH), dim3(512), 0, stream>>>(A_t, Bp_t, att);

  // G4: oute_t[a][e] = sum_m Bh[e][m] * att[a][m]  (B=att f32, converted in staging;
  //     transposed bf16 epilogue). M=256, N=2048, K=2048.
  gemm_nt_mfma<OUT_BF16T, true><<<dim3(16, 2, BATCH), blk, 0, stream>>>(
      Bh, att, oute, 256, 2048, 2048, 524288, 4194304, 524288, 1.f);

  // G5: out[c][a] = sum_e W_out[c][e] * oute_t[a][e]  (M=512,N=2048,K=256) -> f32
  gemm_nt_mfma<OUT_F32, false><<<dim3(16, 4, BATCH), blk, 0, stream>>>(
      wO, oute, out, 512, 2048, 256, 0, 524288, 1048576, 1.f);

  // BatchNorm (training-mode batch stats), two-pass
  bn_stats<<<dim3(CDIM), blk, 0, stream>>>(out, mean, rstd);
  bn_norm<<<dim3(16384), blk, 0, stream>>>(out, mean, rstd, gamma, beta);
}